// Round 1
// baseline (1026.344 us; speedup 1.0000x reference)
//
#include <hip/hip_runtime.h>
#include <math.h>

#define N_NODES 50000
#define N_EDGES 600000
#define DF 128
#define DOUT 40
#define EPSN 1e-5f
#define WAVES 4
#define TROWS 8
#define NODES_PER_BLOCK (WAVES * TROWS)

// ---------------------------------------------------------------------------
// Scatter: one thread per (edge, dim). 600000*128/256 = 300000 blocks exactly.
// ---------------------------------------------------------------------------
__global__ __launch_bounds__(256) void k_scatter(
    const float* __restrict__ h, const int* __restrict__ ei,
    float* __restrict__ msg, float* __restrict__ deg, int addDeg) {
  int t = blockIdx.x * 256 + threadIdx.x;
  int e = t >> 7;
  int d = t & 127;
  int s  = ei[e];            // src row
  int dd = ei[N_EDGES + e];  // dst row
  atomicAdd(&msg[(size_t)dd * DF + d], h[(size_t)s * DF + d]);
  if (addDeg && d == 0) atomicAdd(&deg[dd], 1.0f);
}

// ---------------------------------------------------------------------------
// Fused SAGE linear (D=128 out) + LayerNorm + exact GELU.
// Each wave owns TROWS nodes; rows (agg,x) staged in LDS as float2.
// Lane computes out cols {lane, lane+64}.
// ---------------------------------------------------------------------------
__global__ __launch_bounds__(256) void k_lin128(
    const float* __restrict__ hin, const float* __restrict__ msg,
    const float* __restrict__ deg,
    const float* __restrict__ Wl, const float* __restrict__ bl,
    const float* __restrict__ Wr,
    const float* __restrict__ g, const float* __restrict__ be,
    float* __restrict__ hout) {
  __shared__ float2 rows[WAVES][TROWS][DF];  // 32 KB
  const int wave = threadIdx.x >> 6, lane = threadIdx.x & 63;
  const int n0 = (blockIdx.x * WAVES + wave) * TROWS;

  for (int t = 0; t < TROWS; ++t) {
    int n = n0 + t; if (n > N_NODES - 1) n = N_NODES - 1;  // clamped load
    float rd = 1.0f / fmaxf(deg[n], 1.0f);
    const float* mr = msg + (size_t)n * DF;
    const float* xr = hin + (size_t)n * DF;
    rows[wave][t][lane]      = make_float2(mr[lane] * rd,      xr[lane]);
    rows[wave][t][lane + 64] = make_float2(mr[lane + 64] * rd, xr[lane + 64]);
  }
  __syncthreads();

  float acc0[TROWS], acc1[TROWS];
  {
    float b0 = bl[lane], b1 = bl[lane + 64];
    #pragma unroll
    for (int t = 0; t < TROWS; ++t) { acc0[t] = b0; acc1[t] = b1; }
  }

  #pragma unroll 2
  for (int d = 0; d < DF; ++d) {
    float wl0 = Wl[d * DF + lane];
    float wl1 = Wl[d * DF + 64 + lane];
    float wr0 = Wr[d * DF + lane];
    float wr1 = Wr[d * DF + 64 + lane];
    #pragma unroll
    for (int t = 0; t < TROWS; ++t) {
      float2 ax = rows[wave][t][d];
      acc0[t] = fmaf(ax.x, wl0, fmaf(ax.y, wr0, acc0[t]));
      acc1[t] = fmaf(ax.x, wl1, fmaf(ax.y, wr1, acc1[t]));
    }
  }

  const float gv0 = g[lane], gv1 = g[lane + 64];
  const float bv0 = be[lane], bv1 = be[lane + 64];

  for (int t = 0; t < TROWS; ++t) {
    int n = n0 + t;
    float v0 = acc0[t], v1 = acc1[t];
    float s = v0 + v1, sq = v0 * v0 + v1 * v1;
    #pragma unroll
    for (int m = 1; m < 64; m <<= 1) {
      s  += __shfl_xor(s, m);
      sq += __shfl_xor(sq, m);
    }
    float mu  = s * (1.0f / 128.0f);
    float var = sq * (1.0f / 128.0f) - mu * mu;
    float rs  = rsqrtf(var + EPSN);
    float x0 = (v0 - mu) * rs * gv0 + bv0;
    float x1 = (v1 - mu) * rs * gv1 + bv1;
    v0 = 0.5f * x0 * (1.0f + erff(x0 * 0.70710678118654752f));
    v1 = 0.5f * x1 * (1.0f + erff(x1 * 0.70710678118654752f));
    if (n < N_NODES) {
      hout[(size_t)n * DF + lane]      = v0;
      hout[(size_t)n * DF + 64 + lane] = v1;
    }
  }
}

// ---------------------------------------------------------------------------
// Final SAGE linear (D_OUT=40) + log_softmax. Lanes 0..39 own one out col.
// ---------------------------------------------------------------------------
__global__ __launch_bounds__(256) void k_lin40(
    const float* __restrict__ hin, const float* __restrict__ msg,
    const float* __restrict__ deg,
    const float* __restrict__ Wl, const float* __restrict__ bl,
    const float* __restrict__ Wr,
    float* __restrict__ out) {
  __shared__ float2 rows[WAVES][TROWS][DF];  // 32 KB
  const int wave = threadIdx.x >> 6, lane = threadIdx.x & 63;
  const int n0 = (blockIdx.x * WAVES + wave) * TROWS;

  for (int t = 0; t < TROWS; ++t) {
    int n = n0 + t; if (n > N_NODES - 1) n = N_NODES - 1;
    float rd = 1.0f / fmaxf(deg[n], 1.0f);
    const float* mr = msg + (size_t)n * DF;
    const float* xr = hin + (size_t)n * DF;
    rows[wave][t][lane]      = make_float2(mr[lane] * rd,      xr[lane]);
    rows[wave][t][lane + 64] = make_float2(mr[lane + 64] * rd, xr[lane + 64]);
  }
  __syncthreads();

  const int o = (lane < DOUT) ? lane : 0;
  float acc[TROWS];
  {
    float b = bl[o];
    #pragma unroll
    for (int t = 0; t < TROWS; ++t) acc[t] = b;
  }

  #pragma unroll 2
  for (int d = 0; d < DF; ++d) {
    float wl = Wl[d * DOUT + o];
    float wr = Wr[d * DOUT + o];
    #pragma unroll
    for (int t = 0; t < TROWS; ++t) {
      float2 ax = rows[wave][t][d];
      acc[t] = fmaf(ax.x, wl, fmaf(ax.y, wr, acc[t]));
    }
  }

  for (int t = 0; t < TROWS; ++t) {
    int n = n0 + t;
    float v = (lane < DOUT) ? acc[t] : -INFINITY;
    float m = v;
    #pragma unroll
    for (int k = 1; k < 64; k <<= 1) m = fmaxf(m, __shfl_xor(m, k));
    float ex = (lane < DOUT) ? expf(v - m) : 0.0f;
    float se = ex;
    #pragma unroll
    for (int k = 1; k < 64; k <<= 1) se += __shfl_xor(se, k);
    float r = v - m - logf(se);
    if (lane < DOUT && n < N_NODES) out[(size_t)n * DOUT + lane] = r;
  }
}

// ---------------------------------------------------------------------------
extern "C" void kernel_launch(void* const* d_in, const int* in_sizes, int n_in,
                              void* d_out, int out_size, void* d_ws, size_t ws_size,
                              hipStream_t stream) {
  const float* x   = (const float*)d_in[0];
  const int*   ei  = (const int*)d_in[1];
  const float* Wl0 = (const float*)d_in[2];
  const float* bl0 = (const float*)d_in[3];
  const float* Wr0 = (const float*)d_in[4];
  const float* Wl1 = (const float*)d_in[5];
  const float* bl1 = (const float*)d_in[6];
  const float* Wr1 = (const float*)d_in[7];
  const float* Wl2 = (const float*)d_in[8];
  const float* bl2 = (const float*)d_in[9];
  const float* Wr2 = (const float*)d_in[10];
  const float* g0  = (const float*)d_in[11];
  const float* be0 = (const float*)d_in[12];
  const float* g1  = (const float*)d_in[13];
  const float* be1 = (const float*)d_in[14];
  float* out = (float*)d_out;

  // Workspace: A, B feature/msg buffers (ping-pong), deg.  ~51.5 MB total.
  float* A   = (float*)d_ws;
  float* B   = A + (size_t)N_NODES * DF;
  float* deg = B + (size_t)N_NODES * DF;

  const int sgrid = (N_EDGES * DF) / 256;                               // 300000
  const int lgrid = (N_NODES + NODES_PER_BLOCK - 1) / NODES_PER_BLOCK;  // 1563

  // Layer 0: agg(x) -> A ; h0 = lin(agg, x) +LN+GELU -> A (row-safe alias)
  hipMemsetAsync(A,   0, (size_t)N_NODES * DF * sizeof(float), stream);
  hipMemsetAsync(deg, 0, (size_t)N_NODES * sizeof(float), stream);
  k_scatter<<<sgrid, 256, 0, stream>>>(x, ei, A, deg, 1);
  k_lin128<<<lgrid, 256, 0, stream>>>(x, A, deg, Wl0, bl0, Wr0, g0, be0, A);

  // Layer 1: agg(h0) -> B ; h1 -> B
  hipMemsetAsync(B, 0, (size_t)N_NODES * DF * sizeof(float), stream);
  k_scatter<<<sgrid, 256, 0, stream>>>(A, ei, B, deg, 0);
  k_lin128<<<lgrid, 256, 0, stream>>>(A, B, deg, Wl1, bl1, Wr1, g1, be1, B);

  // Layer 2: agg(h1) -> A ; out = log_softmax(lin40)
  hipMemsetAsync(A, 0, (size_t)N_NODES * DF * sizeof(float), stream);
  k_scatter<<<sgrid, 256, 0, stream>>>(B, ei, A, deg, 0);
  k_lin40<<<lgrid, 256, 0, stream>>>(B, A, deg, Wl2, bl2, Wr2, out);
}

// Round 2
// 607.407 us; speedup vs baseline: 1.6897x; 1.6897x over previous
//
#include <hip/hip_runtime.h>
#include <math.h>

#define N_NODES 50000
#define N_EDGES 600000
#define DF 128
#define DOUT 40
#define EPSN 1e-5f
#define WAVES 4
#define TROWS 8
#define NODES_PER_BLOCK (WAVES * TROWS)

// ---------------------------------------------------------------------------
// CSR build step 1: per-dst edge counts (int atomics, cheap).
// ---------------------------------------------------------------------------
__global__ __launch_bounds__(256) void k_count(
    const int* __restrict__ ei, int* __restrict__ counts) {
  int e = blockIdx.x * 256 + threadIdx.x;
  if (e < N_EDGES) atomicAdd(&counts[ei[N_EDGES + e]], 1);
}

// ---------------------------------------------------------------------------
// CSR build step 2: exclusive prefix sum over 50000 counts, single block.
// Also emits cursor copy (for fill) and invdeg = 1/max(deg,1).
// ---------------------------------------------------------------------------
__global__ __launch_bounds__(1024) void k_scan(
    const int* __restrict__ counts, int* __restrict__ rowptr,
    int* __restrict__ cursor, float* __restrict__ invdeg) {
  __shared__ int part[1024];
  const int t = threadIdx.x;
  const int CH = (N_NODES + 1023) / 1024;  // 49
  const int base = t * CH;

  int s = 0;
  for (int i = 0; i < CH; ++i) {
    int idx = base + i;
    if (idx < N_NODES) s += counts[idx];
  }
  part[t] = s;
  __syncthreads();
  for (int off = 1; off < 1024; off <<= 1) {
    int u = (t >= off) ? part[t - off] : 0;
    __syncthreads();
    part[t] += u;
    __syncthreads();
  }
  int run = part[t] - s;  // exclusive base for this chunk
  for (int i = 0; i < CH; ++i) {
    int idx = base + i;
    if (idx < N_NODES) {
      int c = counts[idx];
      rowptr[idx] = run;
      cursor[idx] = run;
      invdeg[idx] = 1.0f / (float)((c > 1) ? c : 1);
      run += c;
    }
  }
  if (t == 1023) rowptr[N_NODES] = part[1023];
}

// ---------------------------------------------------------------------------
// CSR build step 3: fill adjacency (src ids grouped by dst).
// ---------------------------------------------------------------------------
__global__ __launch_bounds__(256) void k_fill(
    const int* __restrict__ ei, int* __restrict__ cursor, int* __restrict__ csr) {
  int e = blockIdx.x * 256 + threadIdx.x;
  if (e < N_EDGES) {
    int d = ei[N_EDGES + e];
    int p = atomicAdd(&cursor[d], 1);
    csr[p] = ei[e];
  }
}

// ---------------------------------------------------------------------------
// Gather-mean aggregation: one wave per dst node, lanes own dims {l, l+64}.
// Coalesced 512B row reads; h is L2/L3 resident (25.6MB).
// ---------------------------------------------------------------------------
__global__ __launch_bounds__(256) void k_agg(
    const float* __restrict__ h, const int* __restrict__ rowptr,
    const int* __restrict__ csr, const float* __restrict__ invdeg,
    float* __restrict__ msg) {
  const int node = (blockIdx.x * 256 + threadIdx.x) >> 6;
  const int lane = threadIdx.x & 63;
  if (node >= N_NODES) return;
  const int beg = rowptr[node], end = rowptr[node + 1];
  float a0 = 0.0f, a1 = 0.0f;
  for (int j = beg; j < end; ++j) {
    const float* r = h + (size_t)csr[j] * DF;
    a0 += r[lane];
    a1 += r[lane + 64];
  }
  const float rd = invdeg[node];
  msg[(size_t)node * DF + lane]      = a0 * rd;
  msg[(size_t)node * DF + 64 + lane] = a1 * rd;
}

// ---------------------------------------------------------------------------
// Fused SAGE linear (D=128 out) + LayerNorm + exact GELU.
// msg already holds the MEAN aggregate. hout may alias hin/msg (row-safe).
// ---------------------------------------------------------------------------
__global__ __launch_bounds__(256) void k_lin128(
    const float* __restrict__ hin, const float* __restrict__ msg,
    const float* __restrict__ Wl, const float* __restrict__ bl,
    const float* __restrict__ Wr,
    const float* __restrict__ g, const float* __restrict__ be,
    float* __restrict__ hout) {
  __shared__ float2 rows[WAVES][TROWS][DF];  // 32 KB
  const int wave = threadIdx.x >> 6, lane = threadIdx.x & 63;
  const int n0 = (blockIdx.x * WAVES + wave) * TROWS;

  for (int t = 0; t < TROWS; ++t) {
    int n = n0 + t; if (n > N_NODES - 1) n = N_NODES - 1;  // clamped load
    const float* mr = msg + (size_t)n * DF;
    const float* xr = hin + (size_t)n * DF;
    rows[wave][t][lane]      = make_float2(mr[lane],      xr[lane]);
    rows[wave][t][lane + 64] = make_float2(mr[lane + 64], xr[lane + 64]);
  }
  __syncthreads();

  float acc0[TROWS], acc1[TROWS];
  {
    float b0 = bl[lane], b1 = bl[lane + 64];
    #pragma unroll
    for (int t = 0; t < TROWS; ++t) { acc0[t] = b0; acc1[t] = b1; }
  }

  #pragma unroll 2
  for (int d = 0; d < DF; ++d) {
    float wl0 = Wl[d * DF + lane];
    float wl1 = Wl[d * DF + 64 + lane];
    float wr0 = Wr[d * DF + lane];
    float wr1 = Wr[d * DF + 64 + lane];
    #pragma unroll
    for (int t = 0; t < TROWS; ++t) {
      float2 ax = rows[wave][t][d];
      acc0[t] = fmaf(ax.x, wl0, fmaf(ax.y, wr0, acc0[t]));
      acc1[t] = fmaf(ax.x, wl1, fmaf(ax.y, wr1, acc1[t]));
    }
  }

  const float gv0 = g[lane], gv1 = g[lane + 64];
  const float bv0 = be[lane], bv1 = be[lane + 64];

  for (int t = 0; t < TROWS; ++t) {
    int n = n0 + t;
    float v0 = acc0[t], v1 = acc1[t];
    float s = v0 + v1, sq = v0 * v0 + v1 * v1;
    #pragma unroll
    for (int m = 1; m < 64; m <<= 1) {
      s  += __shfl_xor(s, m);
      sq += __shfl_xor(sq, m);
    }
    float mu  = s * (1.0f / 128.0f);
    float var = sq * (1.0f / 128.0f) - mu * mu;
    float rs  = rsqrtf(var + EPSN);
    float x0 = (v0 - mu) * rs * gv0 + bv0;
    float x1 = (v1 - mu) * rs * gv1 + bv1;
    v0 = 0.5f * x0 * (1.0f + erff(x0 * 0.70710678118654752f));
    v1 = 0.5f * x1 * (1.0f + erff(x1 * 0.70710678118654752f));
    if (n < N_NODES) {
      hout[(size_t)n * DF + lane]      = v0;
      hout[(size_t)n * DF + 64 + lane] = v1;
    }
  }
}

// ---------------------------------------------------------------------------
// Final SAGE linear (D_OUT=40) + log_softmax.
// ---------------------------------------------------------------------------
__global__ __launch_bounds__(256) void k_lin40(
    const float* __restrict__ hin, const float* __restrict__ msg,
    const float* __restrict__ Wl, const float* __restrict__ bl,
    const float* __restrict__ Wr,
    float* __restrict__ out) {
  __shared__ float2 rows[WAVES][TROWS][DF];  // 32 KB
  const int wave = threadIdx.x >> 6, lane = threadIdx.x & 63;
  const int n0 = (blockIdx.x * WAVES + wave) * TROWS;

  for (int t = 0; t < TROWS; ++t) {
    int n = n0 + t; if (n > N_NODES - 1) n = N_NODES - 1;
    const float* mr = msg + (size_t)n * DF;
    const float* xr = hin + (size_t)n * DF;
    rows[wave][t][lane]      = make_float2(mr[lane],      xr[lane]);
    rows[wave][t][lane + 64] = make_float2(mr[lane + 64], xr[lane + 64]);
  }
  __syncthreads();

  const int o = (lane < DOUT) ? lane : 0;
  float acc[TROWS];
  {
    float b = bl[o];
    #pragma unroll
    for (int t = 0; t < TROWS; ++t) acc[t] = b;
  }

  #pragma unroll 2
  for (int d = 0; d < DF; ++d) {
    float wl = Wl[d * DOUT + o];
    float wr = Wr[d * DOUT + o];
    #pragma unroll
    for (int t = 0; t < TROWS; ++t) {
      float2 ax = rows[wave][t][d];
      acc[t] = fmaf(ax.x, wl, fmaf(ax.y, wr, acc[t]));
    }
  }

  for (int t = 0; t < TROWS; ++t) {
    int n = n0 + t;
    float v = (lane < DOUT) ? acc[t] : -INFINITY;
    float m = v;
    #pragma unroll
    for (int k = 1; k < 64; k <<= 1) m = fmaxf(m, __shfl_xor(m, k));
    float ex = (lane < DOUT) ? expf(v - m) : 0.0f;
    float se = ex;
    #pragma unroll
    for (int k = 1; k < 64; k <<= 1) se += __shfl_xor(se, k);
    float r = v - m - logf(se);
    if (lane < DOUT && n < N_NODES) out[(size_t)n * DOUT + lane] = r;
  }
}

// ---------------------------------------------------------------------------
extern "C" void kernel_launch(void* const* d_in, const int* in_sizes, int n_in,
                              void* d_out, int out_size, void* d_ws, size_t ws_size,
                              hipStream_t stream) {
  const float* x   = (const float*)d_in[0];
  const int*   ei  = (const int*)d_in[1];
  const float* Wl0 = (const float*)d_in[2];
  const float* bl0 = (const float*)d_in[3];
  const float* Wr0 = (const float*)d_in[4];
  const float* Wl1 = (const float*)d_in[5];
  const float* bl1 = (const float*)d_in[6];
  const float* Wr1 = (const float*)d_in[7];
  const float* Wl2 = (const float*)d_in[8];
  const float* bl2 = (const float*)d_in[9];
  const float* Wr2 = (const float*)d_in[10];
  const float* g0  = (const float*)d_in[11];
  const float* be0 = (const float*)d_in[12];
  const float* g1  = (const float*)d_in[13];
  const float* be1 = (const float*)d_in[14];
  float* out = (float*)d_out;

  // Workspace layout (~54.3 MB):
  float* A      = (float*)d_ws;                       // 50000*128 f32
  float* B      = A + (size_t)N_NODES * DF;           // 50000*128 f32
  float* invdeg = B + (size_t)N_NODES * DF;           // 50000 f32
  int*   counts = (int*)(invdeg + N_NODES);           // 50000
  int*   rowptr = counts + N_NODES;                   // 50001
  int*   cursor = rowptr + N_NODES + 1;               // 50000
  int*   csr    = cursor + N_NODES;                   // 600000

  const int egrid = (N_EDGES + 255) / 256;                              // 2344
  const int agrid = (N_NODES * 64 + 255) / 256;                         // 12500
  const int lgrid = (N_NODES + NODES_PER_BLOCK - 1) / NODES_PER_BLOCK;  // 1563

  // --- CSR build (once per call) ---
  hipMemsetAsync(counts, 0, N_NODES * sizeof(int), stream);
  k_count<<<egrid, 256, 0, stream>>>(ei, counts);
  k_scan<<<1, 1024, 0, stream>>>(counts, rowptr, cursor, invdeg);
  k_fill<<<egrid, 256, 0, stream>>>(ei, cursor, csr);

  // --- Layer 0: agg(x)->A ; h0 = lin(A, x)+LN+GELU -> B ---
  k_agg<<<agrid, 256, 0, stream>>>(x, rowptr, csr, invdeg, A);
  k_lin128<<<lgrid, 256, 0, stream>>>(x, A, Wl0, bl0, Wr0, g0, be0, B);

  // --- Layer 1: agg(h0)->A ; h1 -> B (row-safe alias) ---
  k_agg<<<agrid, 256, 0, stream>>>(B, rowptr, csr, invdeg, A);
  k_lin128<<<lgrid, 256, 0, stream>>>(B, A, Wl1, bl1, Wr1, g1, be1, B);

  // --- Layer 2: agg(h1)->A ; out = log_softmax(lin40) ---
  k_agg<<<agrid, 256, 0, stream>>>(B, rowptr, csr, invdeg, A);
  k_lin40<<<lgrid, 256, 0, stream>>>(B, A, Wl2, bl2, Wr2, out);
}

// Round 3
// 471.377 us; speedup vs baseline: 2.1773x; 1.2886x over previous
//
#include <hip/hip_runtime.h>
#include <math.h>

#define N_NODES 50000
#define N_EDGES 600000
#define DF 128
#define DOUT 40
#define EPSN 1e-5f
#define WAVES 4
#define TROWS 8
#define NODES_PER_BLOCK (WAVES * TROWS)
#define NB1 196  // ceil(50000/256)

// ---------------------------------------------------------------------------
// CSR build step 1: per-dst edge counts (int atomics, cheap).
// ---------------------------------------------------------------------------
__global__ __launch_bounds__(256) void k_count(
    const int* __restrict__ ei, int* __restrict__ counts) {
  int e = blockIdx.x * 256 + threadIdx.x;
  if (e < N_EDGES) atomicAdd(&counts[ei[N_EDGES + e]], 1);
}

// ---------------------------------------------------------------------------
// Scan stage A: per-block (256-elem chunk) sums.
// ---------------------------------------------------------------------------
__global__ __launch_bounds__(256) void k_bsum(
    const int* __restrict__ counts, int* __restrict__ bsum) {
  int i = blockIdx.x * 256 + threadIdx.x;
  int v = (i < N_NODES) ? counts[i] : 0;
  #pragma unroll
  for (int m = 1; m < 64; m <<= 1) v += __shfl_xor(v, m);
  __shared__ int ws[4];
  if ((threadIdx.x & 63) == 0) ws[threadIdx.x >> 6] = v;
  __syncthreads();
  if (threadIdx.x == 0) bsum[blockIdx.x] = ws[0] + ws[1] + ws[2] + ws[3];
}

// ---------------------------------------------------------------------------
// Scan stage B: exclusive scan of NB1 block sums (single small block).
// ---------------------------------------------------------------------------
__global__ __launch_bounds__(256) void k_bscan(
    const int* __restrict__ bsum, int* __restrict__ bbase) {
  const int t = threadIdx.x, lane = t & 63, w = t >> 6;
  int v = (t < NB1) ? bsum[t] : 0;
  int s = v;
  #pragma unroll
  for (int off = 1; off < 64; off <<= 1) {
    int u = __shfl_up(s, off);
    if (lane >= off) s += u;
  }
  __shared__ int wtot[4];
  if (lane == 63) wtot[w] = s;
  __syncthreads();
  int add = 0;
  for (int k = 0; k < w; ++k) add += wtot[k];
  if (t < NB1) bbase[t] = s + add - v;  // exclusive
}

// ---------------------------------------------------------------------------
// Scan stage C: block-local exclusive scan + base -> rowptr/cursor/invdeg.
// ---------------------------------------------------------------------------
__global__ __launch_bounds__(256) void k_rowptr(
    const int* __restrict__ counts, const int* __restrict__ bbase,
    int* __restrict__ rowptr, int* __restrict__ cursor,
    float* __restrict__ invdeg) {
  const int i = blockIdx.x * 256 + threadIdx.x;
  const int lane = threadIdx.x & 63, w = threadIdx.x >> 6;
  int c = (i < N_NODES) ? counts[i] : 0;
  int s = c;
  #pragma unroll
  for (int off = 1; off < 64; off <<= 1) {
    int u = __shfl_up(s, off);
    if (lane >= off) s += u;
  }
  __shared__ int wtot[4];
  if (lane == 63) wtot[w] = s;
  __syncthreads();
  int add = bbase[blockIdx.x];
  for (int k = 0; k < w; ++k) add += wtot[k];
  if (i < N_NODES) {
    int excl = s - c + add;
    rowptr[i] = excl;
    cursor[i] = excl;
    invdeg[i] = 1.0f / (float)((c > 1) ? c : 1);
  }
  if (i == 0) rowptr[N_NODES] = N_EDGES;  // all dst in range
}

// ---------------------------------------------------------------------------
// CSR build step 3: fill adjacency (src ids grouped by dst).
// ---------------------------------------------------------------------------
__global__ __launch_bounds__(256) void k_fill(
    const int* __restrict__ ei, int* __restrict__ cursor, int* __restrict__ csr) {
  int e = blockIdx.x * 256 + threadIdx.x;
  if (e < N_EDGES) {
    int d = ei[N_EDGES + e];
    int p = atomicAdd(&cursor[d], 1);
    csr[p] = ei[e];
  }
}

// ---------------------------------------------------------------------------
// Gather-mean aggregation: one wave per dst node, float2 per lane (128 dims).
// ---------------------------------------------------------------------------
__global__ __launch_bounds__(256) void k_agg(
    const float* __restrict__ h, const int* __restrict__ rowptr,
    const int* __restrict__ csr, const float* __restrict__ invdeg,
    float* __restrict__ msg) {
  const int node = (blockIdx.x * 256 + threadIdx.x) >> 6;
  const int lane = threadIdx.x & 63;
  if (node >= N_NODES) return;
  const int beg = rowptr[node], end = rowptr[node + 1];
  const float2* h2 = (const float2*)h;
  float ax = 0.0f, ay = 0.0f;
  for (int j = beg; j < end; ++j) {
    float2 r = h2[(size_t)csr[j] * 64 + lane];
    ax += r.x; ay += r.y;
  }
  const float rd = invdeg[node];
  ((float2*)msg)[(size_t)node * 64 + lane] = make_float2(ax * rd, ay * rd);
}

// ---------------------------------------------------------------------------
// Fused SAGE linear (D=128 out) + LayerNorm + exact GELU.
// LDS row t holds interleaved (msg, x) pairs: float4(m2k, x2k, m2k1, x2k1).
// ---------------------------------------------------------------------------
__global__ __launch_bounds__(256) void k_lin128(
    const float* __restrict__ hin, const float* __restrict__ msg,
    const float* __restrict__ Wl, const float* __restrict__ bl,
    const float* __restrict__ Wr,
    const float* __restrict__ g, const float* __restrict__ be,
    float* __restrict__ hout) {
  __shared__ float2 rows[WAVES][TROWS][DF];  // 32 KB
  const int wave = threadIdx.x >> 6, lane = threadIdx.x & 63;
  const int n0 = (blockIdx.x * WAVES + wave) * TROWS;

  for (int t = 0; t < TROWS; ++t) {
    int n = n0 + t; if (n > N_NODES - 1) n = N_NODES - 1;  // clamped load
    float2 m2 = ((const float2*)msg)[(size_t)n * 64 + lane];
    float2 x2 = ((const float2*)hin)[(size_t)n * 64 + lane];
    ((float4*)&rows[wave][t][0])[lane] = make_float4(m2.x, x2.x, m2.y, x2.y);
  }
  __syncthreads();

  float acc0[TROWS], acc1[TROWS];
  {
    float b0 = bl[lane], b1 = bl[lane + 64];
    #pragma unroll
    for (int t = 0; t < TROWS; ++t) { acc0[t] = b0; acc1[t] = b1; }
  }

  #pragma unroll 2
  for (int d = 0; d < DF; ++d) {
    float wl0 = Wl[d * DF + lane];
    float wl1 = Wl[d * DF + 64 + lane];
    float wr0 = Wr[d * DF + lane];
    float wr1 = Wr[d * DF + 64 + lane];
    #pragma unroll
    for (int t = 0; t < TROWS; ++t) {
      float2 ax = rows[wave][t][d];
      acc0[t] = fmaf(ax.x, wl0, fmaf(ax.y, wr0, acc0[t]));
      acc1[t] = fmaf(ax.x, wl1, fmaf(ax.y, wr1, acc1[t]));
    }
  }

  const float gv0 = g[lane], gv1 = g[lane + 64];
  const float bv0 = be[lane], bv1 = be[lane + 64];

  for (int t = 0; t < TROWS; ++t) {
    int n = n0 + t;
    float v0 = acc0[t], v1 = acc1[t];
    float s = v0 + v1, sq = v0 * v0 + v1 * v1;
    #pragma unroll
    for (int m = 1; m < 64; m <<= 1) {
      s  += __shfl_xor(s, m);
      sq += __shfl_xor(sq, m);
    }
    float mu  = s * (1.0f / 128.0f);
    float var = sq * (1.0f / 128.0f) - mu * mu;
    float rs  = rsqrtf(var + EPSN);
    float x0 = (v0 - mu) * rs * gv0 + bv0;
    float x1 = (v1 - mu) * rs * gv1 + bv1;
    v0 = 0.5f * x0 * (1.0f + erff(x0 * 0.70710678118654752f));
    v1 = 0.5f * x1 * (1.0f + erff(x1 * 0.70710678118654752f));
    if (n < N_NODES) {
      hout[(size_t)n * DF + lane]      = v0;
      hout[(size_t)n * DF + 64 + lane] = v1;
    }
  }
}

// ---------------------------------------------------------------------------
// Final SAGE linear (D_OUT=40) + log_softmax.
// ---------------------------------------------------------------------------
__global__ __launch_bounds__(256) void k_lin40(
    const float* __restrict__ hin, const float* __restrict__ msg,
    const float* __restrict__ Wl, const float* __restrict__ bl,
    const float* __restrict__ Wr,
    float* __restrict__ out) {
  __shared__ float2 rows[WAVES][TROWS][DF];  // 32 KB
  const int wave = threadIdx.x >> 6, lane = threadIdx.x & 63;
  const int n0 = (blockIdx.x * WAVES + wave) * TROWS;

  for (int t = 0; t < TROWS; ++t) {
    int n = n0 + t; if (n > N_NODES - 1) n = N_NODES - 1;
    float2 m2 = ((const float2*)msg)[(size_t)n * 64 + lane];
    float2 x2 = ((const float2*)hin)[(size_t)n * 64 + lane];
    ((float4*)&rows[wave][t][0])[lane] = make_float4(m2.x, x2.x, m2.y, x2.y);
  }
  __syncthreads();

  const int o = (lane < DOUT) ? lane : 0;
  float acc[TROWS];
  {
    float b = bl[o];
    #pragma unroll
    for (int t = 0; t < TROWS; ++t) acc[t] = b;
  }

  #pragma unroll 2
  for (int d = 0; d < DF; ++d) {
    float wl = Wl[d * DOUT + o];
    float wr = Wr[d * DOUT + o];
    #pragma unroll
    for (int t = 0; t < TROWS; ++t) {
      float2 ax = rows[wave][t][d];
      acc[t] = fmaf(ax.x, wl, fmaf(ax.y, wr, acc[t]));
    }
  }

  for (int t = 0; t < TROWS; ++t) {
    int n = n0 + t;
    float v = (lane < DOUT) ? acc[t] : -INFINITY;
    float m = v;
    #pragma unroll
    for (int k = 1; k < 64; k <<= 1) m = fmaxf(m, __shfl_xor(m, k));
    float ex = (lane < DOUT) ? expf(v - m) : 0.0f;
    float se = ex;
    #pragma unroll
    for (int k = 1; k < 64; k <<= 1) se += __shfl_xor(se, k);
    float r = v - m - logf(se);
    if (lane < DOUT && n < N_NODES) out[(size_t)n * DOUT + lane] = r;
  }
}

// ---------------------------------------------------------------------------
extern "C" void kernel_launch(void* const* d_in, const int* in_sizes, int n_in,
                              void* d_out, int out_size, void* d_ws, size_t ws_size,
                              hipStream_t stream) {
  const float* x   = (const float*)d_in[0];
  const int*   ei  = (const int*)d_in[1];
  const float* Wl0 = (const float*)d_in[2];
  const float* bl0 = (const float*)d_in[3];
  const float* Wr0 = (const float*)d_in[4];
  const float* Wl1 = (const float*)d_in[5];
  const float* bl1 = (const float*)d_in[6];
  const float* Wr1 = (const float*)d_in[7];
  const float* Wl2 = (const float*)d_in[8];
  const float* bl2 = (const float*)d_in[9];
  const float* Wr2 = (const float*)d_in[10];
  const float* g0  = (const float*)d_in[11];
  const float* be0 = (const float*)d_in[12];
  const float* g1  = (const float*)d_in[13];
  const float* be1 = (const float*)d_in[14];
  float* out = (float*)d_out;

  // Workspace layout (~54.3 MB):
  float* A      = (float*)d_ws;                       // 50000*128 f32
  float* B      = A + (size_t)N_NODES * DF;           // 50000*128 f32
  float* invdeg = B + (size_t)N_NODES * DF;           // 50000 f32
  int*   counts = (int*)(invdeg + N_NODES);           // 50000
  int*   rowptr = counts + N_NODES;                   // 50001
  int*   cursor = rowptr + N_NODES + 1;               // 50000
  int*   csr    = cursor + N_NODES;                   // 600000
  int*   bsum   = csr + N_EDGES;                      // NB1
  int*   bbase  = bsum + NB1;                         // NB1

  const int egrid = (N_EDGES + 255) / 256;                              // 2344
  const int agrid = (N_NODES * 64 + 255) / 256;                         // 12500
  const int lgrid = (N_NODES + NODES_PER_BLOCK - 1) / NODES_PER_BLOCK;  // 1563

  // --- CSR build (once per call) ---
  hipMemsetAsync(counts, 0, N_NODES * sizeof(int), stream);
  k_count<<<egrid, 256, 0, stream>>>(ei, counts);
  k_bsum<<<NB1, 256, 0, stream>>>(counts, bsum);
  k_bscan<<<1, 256, 0, stream>>>(bsum, bbase);
  k_rowptr<<<NB1, 256, 0, stream>>>(counts, bbase, rowptr, cursor, invdeg);
  k_fill<<<egrid, 256, 0, stream>>>(ei, cursor, csr);

  // --- Layer 0: agg(x)->A ; h0 = lin(A, x)+LN+GELU -> B ---
  k_agg<<<agrid, 256, 0, stream>>>(x, rowptr, csr, invdeg, A);
  k_lin128<<<lgrid, 256, 0, stream>>>(x, A, Wl0, bl0, Wr0, g0, be0, B);

  // --- Layer 1: agg(h0)->A ; h1 -> B ---
  k_agg<<<agrid, 256, 0, stream>>>(B, rowptr, csr, invdeg, A);
  k_lin128<<<lgrid, 256, 0, stream>>>(B, A, Wl1, bl1, Wr1, g1, be1, B);

  // --- Layer 2: agg(h1)->A ; out = log_softmax(lin40) ---
  k_agg<<<agrid, 256, 0, stream>>>(B, rowptr, csr, invdeg, A);
  k_lin40<<<lgrid, 256, 0, stream>>>(B, A, Wl2, bl2, Wr2, out);
}

// Round 4
// 379.870 us; speedup vs baseline: 2.7018x; 1.2409x over previous
//
#include <hip/hip_runtime.h>
#include <math.h>

#define N_NODES 50000
#define N_EDGES 600000
#define DF 128
#define KK 256
#define DOUT 40
#define EPSN 1e-5f
#define NB1 196  // ceil(50000/256)

typedef __attribute__((ext_vector_type(8))) short sh8;   // 8 bf16 (4 VGPRs)
typedef __attribute__((ext_vector_type(4))) float f32x4;

__device__ __forceinline__ unsigned short f2b(float f) {  // fp32 -> bf16 RNE
  unsigned u = __builtin_bit_cast(unsigned, f);
  unsigned r = u + 0x7FFFu + ((u >> 16) & 1u);
  return (unsigned short)(r >> 16);
}
__device__ __forceinline__ float b2f(unsigned short b) {
  unsigned u = ((unsigned)b) << 16;
  return __builtin_bit_cast(float, u);
}

// ---------------------------------------------------------------------------
// CSR build
// ---------------------------------------------------------------------------
__global__ __launch_bounds__(256) void k_count(
    const int* __restrict__ ei, int* __restrict__ counts) {
  int e = blockIdx.x * 256 + threadIdx.x;
  if (e < N_EDGES) atomicAdd(&counts[ei[N_EDGES + e]], 1);
}

__global__ __launch_bounds__(256) void k_bsum(
    const int* __restrict__ counts, int* __restrict__ bsum) {
  int i = blockIdx.x * 256 + threadIdx.x;
  int v = (i < N_NODES) ? counts[i] : 0;
  #pragma unroll
  for (int m = 1; m < 64; m <<= 1) v += __shfl_xor(v, m);
  __shared__ int ws[4];
  if ((threadIdx.x & 63) == 0) ws[threadIdx.x >> 6] = v;
  __syncthreads();
  if (threadIdx.x == 0) bsum[blockIdx.x] = ws[0] + ws[1] + ws[2] + ws[3];
}

__global__ __launch_bounds__(256) void k_bscan(
    const int* __restrict__ bsum, int* __restrict__ bbase) {
  const int t = threadIdx.x, lane = t & 63, w = t >> 6;
  int v = (t < NB1) ? bsum[t] : 0;
  int s = v;
  #pragma unroll
  for (int off = 1; off < 64; off <<= 1) {
    int u = __shfl_up(s, off);
    if (lane >= off) s += u;
  }
  __shared__ int wtot[4];
  if (lane == 63) wtot[w] = s;
  __syncthreads();
  int add = 0;
  for (int k = 0; k < w; ++k) add += wtot[k];
  if (t < NB1) bbase[t] = s + add - v;  // exclusive
}

__global__ __launch_bounds__(256) void k_rowptr(
    const int* __restrict__ counts, const int* __restrict__ bbase,
    int* __restrict__ rowptr, int* __restrict__ cursor,
    float* __restrict__ invdeg) {
  const int i = blockIdx.x * 256 + threadIdx.x;
  const int lane = threadIdx.x & 63, w = threadIdx.x >> 6;
  int c = (i < N_NODES) ? counts[i] : 0;
  int s = c;
  #pragma unroll
  for (int off = 1; off < 64; off <<= 1) {
    int u = __shfl_up(s, off);
    if (lane >= off) s += u;
  }
  __shared__ int wtot[4];
  if (lane == 63) wtot[w] = s;
  __syncthreads();
  int add = bbase[blockIdx.x];
  for (int k = 0; k < w; ++k) add += wtot[k];
  if (i < N_NODES) {
    int excl = s - c + add;
    rowptr[i] = excl;
    cursor[i] = excl;
    invdeg[i] = 1.0f / (float)((c > 1) ? c : 1);
  }
  if (i == 0) rowptr[N_NODES] = N_EDGES;
}

__global__ __launch_bounds__(256) void k_fill(
    const int* __restrict__ ei, int* __restrict__ cursor, int* __restrict__ csr) {
  int e = blockIdx.x * 256 + threadIdx.x;
  if (e < N_EDGES) {
    int d = ei[N_EDGES + e];
    int p = atomicAdd(&cursor[d], 1);
    csr[p] = ei[e];
  }
}

// ---------------------------------------------------------------------------
// x (fp32) -> bf16 into x-half (cols 128:256) of Acat.
// ---------------------------------------------------------------------------
__global__ __launch_bounds__(256) void k_cvt_x(
    const float* __restrict__ x, unsigned* __restrict__ A) {
  int i = blockIdx.x * 256 + threadIdx.x;  // over N_NODES*64 float2s
  if (i >= N_NODES * 64) return;
  int n = i >> 6, p = i & 63;
  float2 v = ((const float2*)x)[i];
  A[(size_t)n * 128 + 64 + p] = (unsigned)f2b(v.x) | ((unsigned)f2b(v.y) << 16);
}

// ---------------------------------------------------------------------------
// Weight prep: WT[n][k] = bf16( k<128 ? Wl[k][n] : Wr[k-128][n] ), n<Npad.
// ---------------------------------------------------------------------------
__global__ __launch_bounds__(256) void k_cvt_w(
    const float* __restrict__ Wl, const float* __restrict__ Wr,
    unsigned short* __restrict__ WT, int Nact, int total) {
  int i = blockIdx.x * 256 + threadIdx.x;  // over Npad*256
  if (i >= total) return;
  int n = i >> 8, k = i & 255;
  float v = 0.0f;
  if (n < Nact) v = (k < DF) ? Wl[k * Nact + n] : Wr[(k - DF) * Nact + n];
  WT[i] = f2b(v);
}

// ---------------------------------------------------------------------------
// Gather-mean aggregation (bf16): one wave per dst node.
// Reads x-half (uints 64:128) of Acat rows; writes msg-half (uints 0:64).
// ---------------------------------------------------------------------------
__global__ __launch_bounds__(256) void k_agg(
    unsigned* __restrict__ A, const int* __restrict__ rowptr,
    const int* __restrict__ csr, const float* __restrict__ invdeg) {
  const int node = (blockIdx.x * 256 + threadIdx.x) >> 6;
  const int lane = threadIdx.x & 63;
  if (node >= N_NODES) return;
  const int beg = rowptr[node], end = rowptr[node + 1];
  float ax = 0.0f, ay = 0.0f;
  for (int j = beg; j < end; ++j) {
    unsigned pk = A[(size_t)csr[j] * 128 + 64 + lane];
    ax += b2f((unsigned short)pk);
    ay += b2f((unsigned short)(pk >> 16));
  }
  const float rd = invdeg[node];
  A[(size_t)node * 128 + lane] =
      (unsigned)f2b(ax * rd) | ((unsigned)f2b(ay * rd) << 16);
}

// ---------------------------------------------------------------------------
// MFMA GEMM [M=50000, K=256, N=128] + bias + LayerNorm + exact GELU.
// Wave = 16 rows x 128 cols (8 col-frags, 8 K-steps of 16x16x32 bf16).
// No LDS. In-place row-safe: each wave reads only its own 16 rows.
// Writes bf16 result into x-half of Adst.
// ---------------------------------------------------------------------------
__global__ __launch_bounds__(256) void k_gemm128(
    const unsigned short* __restrict__ Acat, const unsigned short* __restrict__ WT,
    const float* __restrict__ bl, const float* __restrict__ g,
    const float* __restrict__ be, unsigned short* __restrict__ Adst) {
  const int wave = threadIdx.x >> 6, lane = threadIdx.x & 63;
  const int lr = lane & 15, lg = lane >> 4;
  const int rw = blockIdx.x * 64 + wave * 16;  // wave's row base
  int arow = rw + lr; if (arow >= N_NODES) arow = N_NODES - 1;

  // A fragments: lane holds A[row=lr][k = ks*32 + lg*8 + i], i=0..7 (16B load)
  const sh8* Ap = (const sh8*)(Acat + (size_t)arow * KK + lg * 8);
  sh8 a[8];
  #pragma unroll
  for (int ks = 0; ks < 8; ++ks) a[ks] = Ap[ks * 4];  // 32 shorts = 4 sh8

  // B fragments: lane holds B[k][col = n0+lr] from WT[col][k] (N-major)
  const sh8* Bp = (const sh8*)(WT + (size_t)lr * KK + lg * 8);
  f32x4 accs[8];
  #pragma unroll
  for (int f = 0; f < 8; ++f) {
    f32x4 acc = {0.f, 0.f, 0.f, 0.f};
    #pragma unroll
    for (int ks = 0; ks < 8; ++ks) {
      sh8 b = Bp[f * 512 + ks * 4];  // f stride = 16 cols * 256 k = 4096 shorts
      acc = __builtin_amdgcn_mfma_f32_16x16x32_bf16(a[ks], b, acc, 0, 0, 0);
    }
    accs[f] = acc;
  }

  // Epilogue: bias, LN over 128 cols (row = rw + lg*4 + r), GELU, bf16 store.
  float vals[8][4];
  float s[4] = {0, 0, 0, 0}, sq[4] = {0, 0, 0, 0};
  #pragma unroll
  for (int f = 0; f < 8; ++f) {
    float bc = bl[lr + 16 * f];
    #pragma unroll
    for (int r = 0; r < 4; ++r) {
      float v = accs[f][r] + bc;
      vals[f][r] = v;
      s[r] += v; sq[r] += v * v;
    }
  }
  #pragma unroll
  for (int m = 1; m < 16; m <<= 1) {
    #pragma unroll
    for (int r = 0; r < 4; ++r) {
      s[r]  += __shfl_xor(s[r], m);
      sq[r] += __shfl_xor(sq[r], m);
    }
  }
  float mu[4], rs[4];
  #pragma unroll
  for (int r = 0; r < 4; ++r) {
    mu[r] = s[r] * (1.0f / 128.0f);
    float var = sq[r] * (1.0f / 128.0f) - mu[r] * mu[r];
    rs[r] = rsqrtf(var + EPSN);
  }
  #pragma unroll
  for (int f = 0; f < 8; ++f) {
    float gv = g[lr + 16 * f], bev = be[lr + 16 * f];
    #pragma unroll
    for (int r = 0; r < 4; ++r) {
      int row = rw + lg * 4 + r;
      float xn = (vals[f][r] - mu[r]) * rs[r] * gv + bev;
      float gel = 0.5f * xn * (1.0f + erff(xn * 0.70710678118654752f));
      if (row < N_NODES)
        Adst[(size_t)row * KK + 128 + lr + 16 * f] = f2b(gel);
    }
  }
}

// ---------------------------------------------------------------------------
// Final MFMA GEMM [M=50000, K=256, N=48(pad of 40)] + bias + log_softmax.
// ---------------------------------------------------------------------------
__global__ __launch_bounds__(256) void k_gemm40(
    const unsigned short* __restrict__ Acat, const unsigned short* __restrict__ WT,
    const float* __restrict__ bl, float* __restrict__ out) {
  const int wave = threadIdx.x >> 6, lane = threadIdx.x & 63;
  const int lr = lane & 15, lg = lane >> 4;
  const int rw = blockIdx.x * 64 + wave * 16;
  int arow = rw + lr; if (arow >= N_NODES) arow = N_NODES - 1;

  const sh8* Ap = (const sh8*)(Acat + (size_t)arow * KK + lg * 8);
  sh8 a[8];
  #pragma unroll
  for (int ks = 0; ks < 8; ++ks) a[ks] = Ap[ks * 4];

  const sh8* Bp = (const sh8*)(WT + (size_t)lr * KK + lg * 8);
  f32x4 accs[3];
  #pragma unroll
  for (int f = 0; f < 3; ++f) {
    f32x4 acc = {0.f, 0.f, 0.f, 0.f};
    #pragma unroll
    for (int ks = 0; ks < 8; ++ks) {
      sh8 b = Bp[f * 512 + ks * 4];
      acc = __builtin_amdgcn_mfma_f32_16x16x32_bf16(a[ks], b, acc, 0, 0, 0);
    }
    accs[f] = acc;
  }

  // cols: f=0 -> lr, f=1 -> 16+lr, f=2 -> 32+lr (valid only lr<8)
  const bool v2 = (lr < 8);
  float vals[3][4];
  #pragma unroll
  for (int f = 0; f < 3; ++f) {
    int col = lr + 16 * f;
    float bc = (col < DOUT) ? bl[col] : 0.0f;
    #pragma unroll
    for (int r = 0; r < 4; ++r) vals[f][r] = accs[f][r] + bc;
  }
  #pragma unroll
  for (int r = 0; r < 4; ++r) {
    float m = fmaxf(vals[0][r], vals[1][r]);
    if (v2) m = fmaxf(m, vals[2][r]);
    #pragma unroll
    for (int k = 1; k < 16; k <<= 1) m = fmaxf(m, __shfl_xor(m, k));
    float se = expf(vals[0][r] - m) + expf(vals[1][r] - m) +
               (v2 ? expf(vals[2][r] - m) : 0.0f);
    #pragma unroll
    for (int k = 1; k < 16; k <<= 1) se += __shfl_xor(se, k);
    float lse = m + logf(se);
    int row = rw + lg * 4 + r;
    if (row < N_NODES) {
      out[(size_t)row * DOUT + lr]      = vals[0][r] - lse;
      out[(size_t)row * DOUT + 16 + lr] = vals[1][r] - lse;
      if (v2) out[(size_t)row * DOUT + 32 + lr] = vals[2][r] - lse;
    }
  }
}

// ---------------------------------------------------------------------------
extern "C" void kernel_launch(void* const* d_in, const int* in_sizes, int n_in,
                              void* d_out, int out_size, void* d_ws, size_t ws_size,
                              hipStream_t stream) {
  const float* x   = (const float*)d_in[0];
  const int*   ei  = (const int*)d_in[1];
  const float* Wl0 = (const float*)d_in[2];
  const float* bl0 = (const float*)d_in[3];
  const float* Wr0 = (const float*)d_in[4];
  const float* Wl1 = (const float*)d_in[5];
  const float* bl1 = (const float*)d_in[6];
  const float* Wr1 = (const float*)d_in[7];
  const float* Wl2 = (const float*)d_in[8];
  const float* bl2 = (const float*)d_in[9];
  const float* Wr2 = (const float*)d_in[10];
  const float* g0  = (const float*)d_in[11];
  const float* be0 = (const float*)d_in[12];
  const float* g1  = (const float*)d_in[13];
  const float* be1 = (const float*)d_in[14];
  float* out = (float*)d_out;

  // Workspace (~29 MB): single bf16 [50000][256] feature buffer (in-place),
  // 3 transposed bf16 weight blocks, CSR arrays.
  unsigned short* A   = (unsigned short*)d_ws;        // 50000*256 bf16
  unsigned short* WT0 = A + (size_t)N_NODES * KK;     // 128*256
  unsigned short* WT1 = WT0 + 128 * KK;               // 128*256
  unsigned short* WT2 = WT1 + 128 * KK;               // 48*256
  float* invdeg = (float*)(WT2 + 48 * KK);            // 50000
  int*   counts = (int*)(invdeg + N_NODES);           // 50000
  int*   rowptr = counts + N_NODES;                   // 50001
  int*   cursor = rowptr + N_NODES + 1;               // 50000
  int*   csr    = cursor + N_NODES;                   // 600000
  int*   bsum   = csr + N_EDGES;                      // NB1
  int*   bbase  = bsum + NB1;                         // NB1

  const int egrid = (N_EDGES + 255) / 256;   // 2344
  const int xgrid = (N_NODES * 64) / 256;    // 12500
  const int agrid = (N_NODES * 64) / 256;    // 12500 (wave per node)
  const int ggrid = (N_NODES + 63) / 64;     // 782

  // --- CSR build ---
  hipMemsetAsync(counts, 0, N_NODES * sizeof(int), stream);
  k_count<<<egrid, 256, 0, stream>>>(ei, counts);
  k_bsum<<<NB1, 256, 0, stream>>>(counts, bsum);
  k_bscan<<<1, 256, 0, stream>>>(bsum, bbase);
  k_rowptr<<<NB1, 256, 0, stream>>>(counts, bbase, rowptr, cursor, invdeg);
  k_fill<<<egrid, 256, 0, stream>>>(ei, cursor, csr);

  // --- one-time converts ---
  k_cvt_x<<<xgrid, 256, 0, stream>>>(x, (unsigned*)A);
  k_cvt_w<<<128, 256, 0, stream>>>(Wl0, Wr0, WT0, 128, 128 * KK);
  k_cvt_w<<<128, 256, 0, stream>>>(Wl1, Wr1, WT1, 128, 128 * KK);
  k_cvt_w<<<48, 256, 0, stream>>>(Wl2, Wr2, WT2, DOUT, 48 * KK);

  // --- Layer 0 ---
  k_agg<<<agrid, 256, 0, stream>>>((unsigned*)A, rowptr, csr, invdeg);
  k_gemm128<<<ggrid, 256, 0, stream>>>(A, WT0, bl0, g0, be0, A);

  // --- Layer 1 ---
  k_agg<<<agrid, 256, 0, stream>>>((unsigned*)A, rowptr, csr, invdeg);
  k_gemm128<<<ggrid, 256, 0, stream>>>(A, WT1, bl1, g1, be1, A);

  // --- Layer 2 ---
  k_agg<<<agrid, 256, 0, stream>>>((unsigned*)A, rowptr, csr, invdeg);
  k_gemm40<<<ggrid, 256, 0, stream>>>(A, WT2, bl2, out);
}

// Round 5
// 243.060 us; speedup vs baseline: 4.2226x; 1.5629x over previous
//
#include <hip/hip_runtime.h>
#include <math.h>

#define N_NODES 50000
#define N_EDGES 600000
#define DF 128
#define KK 256
#define DOUT 40
#define EPSN 1e-5f
#define NB1 196  // ceil(50000/256)

typedef __attribute__((ext_vector_type(8))) short sh8;   // 8 bf16 (4 VGPRs)
typedef __attribute__((ext_vector_type(4))) float f32x4;

__device__ __forceinline__ unsigned short f2b(float f) {  // fp32 -> bf16 RNE
  unsigned u = __builtin_bit_cast(unsigned, f);
  unsigned r = u + 0x7FFFu + ((u >> 16) & 1u);
  return (unsigned short)(r >> 16);
}
__device__ __forceinline__ float b2f(unsigned short b) {
  unsigned u = ((unsigned)b) << 16;
  return __builtin_bit_cast(float, u);
}

// ---------------------------------------------------------------------------
// CSR build
// ---------------------------------------------------------------------------
__global__ __launch_bounds__(256) void k_count(
    const int* __restrict__ ei, int* __restrict__ counts) {
  int e = blockIdx.x * 256 + threadIdx.x;
  if (e < N_EDGES) atomicAdd(&counts[ei[N_EDGES + e]], 1);
}

__global__ __launch_bounds__(256) void k_bsum(
    const int* __restrict__ counts, int* __restrict__ bsum) {
  int i = blockIdx.x * 256 + threadIdx.x;
  int v = (i < N_NODES) ? counts[i] : 0;
  #pragma unroll
  for (int m = 1; m < 64; m <<= 1) v += __shfl_xor(v, m);
  __shared__ int ws[4];
  if ((threadIdx.x & 63) == 0) ws[threadIdx.x >> 6] = v;
  __syncthreads();
  if (threadIdx.x == 0) bsum[blockIdx.x] = ws[0] + ws[1] + ws[2] + ws[3];
}

__global__ __launch_bounds__(256) void k_bscan(
    const int* __restrict__ bsum, int* __restrict__ bbase) {
  const int t = threadIdx.x, lane = t & 63, w = t >> 6;
  int v = (t < NB1) ? bsum[t] : 0;
  int s = v;
  #pragma unroll
  for (int off = 1; off < 64; off <<= 1) {
    int u = __shfl_up(s, off);
    if (lane >= off) s += u;
  }
  __shared__ int wtot[4];
  if (lane == 63) wtot[w] = s;
  __syncthreads();
  int add = 0;
  for (int k = 0; k < w; ++k) add += wtot[k];
  if (t < NB1) bbase[t] = s + add - v;  // exclusive
}

__global__ __launch_bounds__(256) void k_rowptr(
    const int* __restrict__ counts, const int* __restrict__ bbase,
    int* __restrict__ rowptr, int* __restrict__ cursor,
    float* __restrict__ invdeg) {
  const int i = blockIdx.x * 256 + threadIdx.x;
  const int lane = threadIdx.x & 63, w = threadIdx.x >> 6;
  int c = (i < N_NODES) ? counts[i] : 0;
  int s = c;
  #pragma unroll
  for (int off = 1; off < 64; off <<= 1) {
    int u = __shfl_up(s, off);
    if (lane >= off) s += u;
  }
  __shared__ int wtot[4];
  if (lane == 63) wtot[w] = s;
  __syncthreads();
  int add = bbase[blockIdx.x];
  for (int k = 0; k < w; ++k) add += wtot[k];
  if (i < N_NODES) {
    int excl = s - c + add;
    rowptr[i] = excl;
    cursor[i] = excl;
    invdeg[i] = 1.0f / (float)((c > 1) ? c : 1);
  }
  if (i == 0) rowptr[N_NODES] = N_EDGES;
}

__global__ __launch_bounds__(256) void k_fill(
    const int* __restrict__ ei, int* __restrict__ cursor, int* __restrict__ csr) {
  int e = blockIdx.x * 256 + threadIdx.x;
  if (e < N_EDGES) {
    int d = ei[N_EDGES + e];
    int p = atomicAdd(&cursor[d], 1);
    csr[p] = ei[e];
  }
}

// ---------------------------------------------------------------------------
// x (fp32) -> bf16 into x-half (cols 128:256) of Acat.
// ---------------------------------------------------------------------------
__global__ __launch_bounds__(256) void k_cvt_x(
    const float* __restrict__ x, unsigned* __restrict__ A) {
  int i = blockIdx.x * 256 + threadIdx.x;  // over N_NODES*64 float2s
  if (i >= N_NODES * 64) return;
  int n = i >> 6, p = i & 63;
  float2 v = ((const float2*)x)[i];
  A[(size_t)n * 128 + 64 + p] = (unsigned)f2b(v.x) | ((unsigned)f2b(v.y) << 16);
}

// ---------------------------------------------------------------------------
// Weight prep: WT[n][k] = bf16( k<128 ? Wl[k][n] : Wr[k-128][n] ), n<Npad.
// ---------------------------------------------------------------------------
__global__ __launch_bounds__(256) void k_cvt_w(
    const float* __restrict__ Wl, const float* __restrict__ Wr,
    unsigned short* __restrict__ WT, int Nact, int total) {
  int i = blockIdx.x * 256 + threadIdx.x;  // over Npad*256
  if (i >= total) return;
  int n = i >> 8, k = i & 255;
  float v = 0.0f;
  if (n < Nact) v = (k < DF) ? Wl[k * Nact + n] : Wr[(k - DF) * Nact + n];
  WT[i] = f2b(v);
}

// ---------------------------------------------------------------------------
// Gather-mean aggregation (bf16): one wave per dst node, 4-way ILP unroll.
// Reads x-half (uints 64:128) of Acat rows; writes msg-half (uints 0:64).
// ---------------------------------------------------------------------------
__global__ __launch_bounds__(256) void k_agg(
    unsigned* __restrict__ A, const int* __restrict__ rowptr,
    const int* __restrict__ csr, const float* __restrict__ invdeg) {
  const int node = (blockIdx.x * 256 + threadIdx.x) >> 6;
  const int lane = threadIdx.x & 63;
  if (node >= N_NODES) return;
  const int beg = rowptr[node], end = rowptr[node + 1];
  float ax = 0.f, ay = 0.f, bx = 0.f, by = 0.f;
  float cx = 0.f, cy = 0.f, dx = 0.f, dy = 0.f;
  int j = beg;
  for (; j + 4 <= end; j += 4) {
    int c0 = csr[j], c1 = csr[j + 1], c2 = csr[j + 2], c3 = csr[j + 3];
    unsigned p0 = A[(size_t)c0 * 128 + 64 + lane];
    unsigned p1 = A[(size_t)c1 * 128 + 64 + lane];
    unsigned p2 = A[(size_t)c2 * 128 + 64 + lane];
    unsigned p3 = A[(size_t)c3 * 128 + 64 + lane];
    ax += b2f((unsigned short)p0); ay += b2f((unsigned short)(p0 >> 16));
    bx += b2f((unsigned short)p1); by += b2f((unsigned short)(p1 >> 16));
    cx += b2f((unsigned short)p2); cy += b2f((unsigned short)(p2 >> 16));
    dx += b2f((unsigned short)p3); dy += b2f((unsigned short)(p3 >> 16));
  }
  for (; j < end; ++j) {
    unsigned p = A[(size_t)csr[j] * 128 + 64 + lane];
    ax += b2f((unsigned short)p); ay += b2f((unsigned short)(p >> 16));
  }
  ax += bx + cx + dx;
  ay += by + cy + dy;
  const float rd = invdeg[node];
  A[(size_t)node * 128 + lane] =
      (unsigned)f2b(ax * rd) | ((unsigned)f2b(ay * rd) << 16);
}

// ---------------------------------------------------------------------------
// MFMA GEMM [M=50000, K=256, N=128] + bias + LayerNorm + exact GELU.
// Block = 128 rows (4 waves x 32 rows). W staged in LDS (64KB, XOR-swizzled
// to kill the 512B-stride bank conflict). In-place row-safe.
// ---------------------------------------------------------------------------
__global__ __launch_bounds__(256) void k_gemm128(
    const unsigned short* __restrict__ Acat, const unsigned short* __restrict__ WT,
    const float* __restrict__ bl, const float* __restrict__ g,
    const float* __restrict__ be, unsigned short* __restrict__ Adst) {
  __shared__ unsigned short Wlds[128 * KK];  // 64 KB
  const int t = threadIdx.x;
  #pragma unroll
  for (int it = 0; it < 16; ++it) {
    int c = it * 256 + t;          // 16B-chunk id (4096 total)
    int n = c >> 5, k16 = c & 31;  // n = W output col, k16 = 16B unit in K
    sh8 v = *(const sh8*)(WT + (size_t)n * KK + k16 * 8);
    unsigned off = (unsigned)((n * 512 + k16 * 16) ^ ((n & 7) << 4));
    *(sh8*)((char*)Wlds + off) = v;
  }
  __syncthreads();

  const int wave = t >> 6, lane = t & 63;
  const int lr = lane & 15, lg = lane >> 4;
  const int rw = blockIdx.x * 128 + wave * 32;

  // A fragments: 2 row-frags x 8 K-steps, direct 16B global loads.
  sh8 a[2][8];
  #pragma unroll
  for (int rf = 0; rf < 2; ++rf) {
    int arow = rw + rf * 16 + lr;
    if (arow >= N_NODES) arow = N_NODES - 1;  // clamp within own block
    const sh8* Ap = (const sh8*)(Acat + (size_t)arow * KK + lg * 8);
    #pragma unroll
    for (int ks = 0; ks < 8; ++ks) a[rf][ks] = Ap[ks * 4];
  }

  f32x4 accs[2][8];
  #pragma unroll
  for (int rf = 0; rf < 2; ++rf)
    #pragma unroll
    for (int f = 0; f < 8; ++f) accs[rf][f] = (f32x4){0.f, 0.f, 0.f, 0.f};

  #pragma unroll
  for (int f = 0; f < 8; ++f) {
    const int n = f * 16 + lr;
    const unsigned swz = (unsigned)((n & 7) << 4);
    #pragma unroll
    for (int ks = 0; ks < 8; ++ks) {
      unsigned off = (unsigned)(n * 512 + ks * 64 + lg * 16) ^ swz;
      sh8 b = *(const sh8*)((const char*)Wlds + off);
      accs[0][f] = __builtin_amdgcn_mfma_f32_16x16x32_bf16(a[0][ks], b, accs[0][f], 0, 0, 0);
      accs[1][f] = __builtin_amdgcn_mfma_f32_16x16x32_bf16(a[1][ks], b, accs[1][f], 0, 0, 0);
    }
  }

  // Epilogue: bias + LN + GELU per row-frag; C/D layout col=lr, row=lg*4+r.
  #pragma unroll
  for (int rf = 0; rf < 2; ++rf) {
    float s[4] = {0, 0, 0, 0}, sq[4] = {0, 0, 0, 0};
    #pragma unroll
    for (int f = 0; f < 8; ++f) {
      float bc = bl[lr + 16 * f];
      #pragma unroll
      for (int r = 0; r < 4; ++r) {
        float v = accs[rf][f][r] + bc;
        accs[rf][f][r] = v;
        s[r] += v; sq[r] += v * v;
      }
    }
    #pragma unroll
    for (int m = 1; m < 16; m <<= 1) {
      #pragma unroll
      for (int r = 0; r < 4; ++r) {
        s[r]  += __shfl_xor(s[r], m);
        sq[r] += __shfl_xor(sq[r], m);
      }
    }
    #pragma unroll
    for (int r = 0; r < 4; ++r) {
      float mu = s[r] * (1.0f / 128.0f);
      float var = sq[r] * (1.0f / 128.0f) - mu * mu;
      float rs = rsqrtf(var + EPSN);
      s[r] = mu; sq[r] = rs;  // reuse
    }
    #pragma unroll
    for (int f = 0; f < 8; ++f) {
      float gv = g[lr + 16 * f], bev = be[lr + 16 * f];
      #pragma unroll
      for (int r = 0; r < 4; ++r) {
        int row = rw + rf * 16 + lg * 4 + r;
        float xn = (accs[rf][f][r] - s[r]) * sq[r] * gv + bev;
        float gel = 0.5f * xn * (1.0f + erff(xn * 0.70710678118654752f));
        if (row < N_NODES)
          Adst[(size_t)row * KK + 128 + lr + 16 * f] = f2b(gel);
      }
    }
  }
}

// ---------------------------------------------------------------------------
// Final MFMA GEMM [M=50000, K=256, N=48(pad 40)] + bias + log_softmax.
// ---------------------------------------------------------------------------
__global__ __launch_bounds__(256) void k_gemm40(
    const unsigned short* __restrict__ Acat, const unsigned short* __restrict__ WT,
    const float* __restrict__ bl, float* __restrict__ out) {
  __shared__ unsigned short Wlds[48 * KK];  // 24 KB
  const int t = threadIdx.x;
  #pragma unroll
  for (int it = 0; it < 6; ++it) {
    int c = it * 256 + t;          // 1536 chunks
    int n = c >> 5, k16 = c & 31;
    sh8 v = *(const sh8*)(WT + (size_t)n * KK + k16 * 8);
    unsigned off = (unsigned)((n * 512 + k16 * 16) ^ ((n & 7) << 4));
    *(sh8*)((char*)Wlds + off) = v;
  }
  __syncthreads();

  const int wave = t >> 6, lane = t & 63;
  const int lr = lane & 15, lg = lane >> 4;
  const int rw = blockIdx.x * 128 + wave * 32;

  sh8 a[2][8];
  #pragma unroll
  for (int rf = 0; rf < 2; ++rf) {
    int arow = rw + rf * 16 + lr;
    if (arow >= N_NODES) arow = N_NODES - 1;
    const sh8* Ap = (const sh8*)(Acat + (size_t)arow * KK + lg * 8);
    #pragma unroll
    for (int ks = 0; ks < 8; ++ks) a[rf][ks] = Ap[ks * 4];
  }

  f32x4 accs[2][3];
  #pragma unroll
  for (int rf = 0; rf < 2; ++rf)
    #pragma unroll
    for (int f = 0; f < 3; ++f) accs[rf][f] = (f32x4){0.f, 0.f, 0.f, 0.f};

  #pragma unroll
  for (int f = 0; f < 3; ++f) {
    const int n = f * 16 + lr;
    const unsigned swz = (unsigned)((n & 7) << 4);
    #pragma unroll
    for (int ks = 0; ks < 8; ++ks) {
      unsigned off = (unsigned)(n * 512 + ks * 64 + lg * 16) ^ swz;
      sh8 b = *(const sh8*)((const char*)Wlds + off);
      accs[0][f] = __builtin_amdgcn_mfma_f32_16x16x32_bf16(a[0][ks], b, accs[0][f], 0, 0, 0);
      accs[1][f] = __builtin_amdgcn_mfma_f32_16x16x32_bf16(a[1][ks], b, accs[1][f], 0, 0, 0);
    }
  }

  const bool v2 = (lr < 8);
  #pragma unroll
  for (int rf = 0; rf < 2; ++rf) {
    float vals[3][4];
    #pragma unroll
    for (int f = 0; f < 3; ++f) {
      int col = lr + 16 * f;
      float bc = (col < DOUT) ? bl[col] : 0.0f;
      #pragma unroll
      for (int r = 0; r < 4; ++r) vals[f][r] = accs[rf][f][r] + bc;
    }
    #pragma unroll
    for (int r = 0; r < 4; ++r) {
      float m = fmaxf(vals[0][r], vals[1][r]);
      if (v2) m = fmaxf(m, vals[2][r]);
      #pragma unroll
      for (int k = 1; k < 16; k <<= 1) m = fmaxf(m, __shfl_xor(m, k));
      float se = expf(vals[0][r] - m) + expf(vals[1][r] - m) +
                 (v2 ? expf(vals[2][r] - m) : 0.0f);
      #pragma unroll
      for (int k = 1; k < 16; k <<= 1) se += __shfl_xor(se, k);
      float lse = m + logf(se);
      int row = rw + rf * 16 + lg * 4 + r;
      if (row < N_NODES) {
        out[(size_t)row * DOUT + lr]      = vals[0][r] - lse;
        out[(size_t)row * DOUT + 16 + lr] = vals[1][r] - lse;
        if (v2) out[(size_t)row * DOUT + 32 + lr] = vals[2][r] - lse;
      }
    }
  }
}

// ---------------------------------------------------------------------------
extern "C" void kernel_launch(void* const* d_in, const int* in_sizes, int n_in,
                              void* d_out, int out_size, void* d_ws, size_t ws_size,
                              hipStream_t stream) {
  const float* x   = (const float*)d_in[0];
  const int*   ei  = (const int*)d_in[1];
  const float* Wl0 = (const float*)d_in[2];
  const float* bl0 = (const float*)d_in[3];
  const float* Wr0 = (const float*)d_in[4];
  const float* Wl1 = (const float*)d_in[5];
  const float* bl1 = (const float*)d_in[6];
  const float* Wr1 = (const float*)d_in[7];
  const float* Wl2 = (const float*)d_in[8];
  const float* bl2 = (const float*)d_in[9];
  const float* Wr2 = (const float*)d_in[10];
  const float* g0  = (const float*)d_in[11];
  const float* be0 = (const float*)d_in[12];
  const float* g1  = (const float*)d_in[13];
  const float* be1 = (const float*)d_in[14];
  float* out = (float*)d_out;

  unsigned short* A   = (unsigned short*)d_ws;        // 50000*256 bf16
  unsigned short* WT0 = A + (size_t)N_NODES * KK;     // 128*256
  unsigned short* WT1 = WT0 + 128 * KK;               // 128*256
  unsigned short* WT2 = WT1 + 128 * KK;               // 48*256
  float* invdeg = (float*)(WT2 + 48 * KK);            // 50000
  int*   counts = (int*)(invdeg + N_NODES);           // 50000
  int*   rowptr = counts + N_NODES;                   // 50001
  int*   cursor = rowptr + N_NODES + 1;               // 50000
  int*   csr    = cursor + N_NODES;                   // 600000
  int*   bsum   = csr + N_EDGES;                      // NB1
  int*   bbase  = bsum + NB1;                         // NB1

  const int egrid = (N_EDGES + 255) / 256;    // 2344
  const int xgrid = (N_NODES * 64) / 256;     // 12500
  const int agrid = (N_NODES * 64) / 256;     // 12500 (wave per node)
  const int ggrid = (N_NODES + 127) / 128;    // 391

  // --- CSR build ---
  hipMemsetAsync(counts, 0, N_NODES * sizeof(int), stream);
  k_count<<<egrid, 256, 0, stream>>>(ei, counts);
  k_bsum<<<NB1, 256, 0, stream>>>(counts, bsum);
  k_bscan<<<1, 256, 0, stream>>>(bsum, bbase);
  k_rowptr<<<NB1, 256, 0, stream>>>(counts, bbase, rowptr, cursor, invdeg);
  k_fill<<<egrid, 256, 0, stream>>>(ei, cursor, csr);

  // --- one-time converts ---
  k_cvt_x<<<xgrid, 256, 0, stream>>>(x, (unsigned*)A);
  k_cvt_w<<<128, 256, 0, stream>>>(Wl0, Wr0, WT0, 128, 128 * KK);
  k_cvt_w<<<128, 256, 0, stream>>>(Wl1, Wr1, WT1, 128, 128 * KK);
  k_cvt_w<<<48, 256, 0, stream>>>(Wl2, Wr2, WT2, DOUT, 48 * KK);

  // --- Layer 0 ---
  k_agg<<<agrid, 256, 0, stream>>>((unsigned*)A, rowptr, csr, invdeg);
  k_gemm128<<<ggrid, 256, 0, stream>>>(A, WT0, bl0, g0, be0, A);

  // --- Layer 1 ---
  k_agg<<<agrid, 256, 0, stream>>>((unsigned*)A, rowptr, csr, invdeg);
  k_gemm128<<<ggrid, 256, 0, stream>>>(A, WT1, bl1, g1, be1, A);

  // --- Layer 2 ---
  k_agg<<<agrid, 256, 0, stream>>>((unsigned*)A, rowptr, csr, invdeg);
  k_gemm40<<<ggrid, 256, 0, stream>>>(A, WT2, bl2, out);
}